// Round 8
// baseline (11995.994 us; speedup 1.0000x reference)
//
#include <hip/hip_runtime.h>
#include <math.h>

#define Tn 256
#define Bn 64
#define Hn 512
#define CHUNK 64
#define EPSF 1e-15f
#define NGRP 16     // independent barrier groups
#define GPB 16      // blocks per group
#define NBATCH 4    // batches per group (1 wave per batch in chain phases)
#define HPAD 516    // LDS row stride (floats)
#define FSTRIDE 32  // counter stride (uints) = 128B
#define LOG2E 1.4426950408889634f

typedef float f32x2 __attribute__((ext_vector_type(2)));

// ---- hardware transcendentals (v_exp/v_log/v_rcp) with series guards ----
__device__ __forceinline__ float exp2_hw(float x){ float r; asm("v_exp_f32 %0, %1" : "=v"(r) : "v"(x)); return r; }
__device__ __forceinline__ float log2_hw(float x){ float r; asm("v_log_f32 %0, %1" : "=v"(r) : "v"(x)); return r; }
__device__ __forceinline__ float rcp_hw (float x){ float r; asm("v_rcp_f32 %0, %1" : "=v"(r) : "v"(x)); return r; }

__device__ __forceinline__ float artanh_fast(float x){   // x >= 0
  const float xc = fminf(x, 1.0f - 1e-7f);
  const float big = 0.34657359028f * (log2_hw(1.f + xc) - log2_hw(1.f - xc));
  const float x2 = x*x;
  const float small = x*(1.f + x2*(0.33333333f + x2*0.2f));
  return (x < 0.01f) ? small : big;
}
__device__ __forceinline__ float tanh_fast(float y){     // y >= 0
  const float t = exp2_hw(-2.f*LOG2E*y);
  const float big = (1.f - t) / (1.f + t);
  const float small = y*(1.f - 0.33333333f*y*y);
  return (y < 0.01f) ? small : big;
}
__device__ __forceinline__ float sigmoid_fast(float x){
  return rcp_hw(1.f + exp2_hw(-LOG2E*x));
}

// full-wave butterfly reduce of N values; every lane ends with the total.
template<int N>
__device__ __forceinline__ void red64N(float* v){
  #pragma unroll
  for (int off = 1; off < 64; off <<= 1){
    #pragma unroll
    for (int n = 0; n < N; ++n) v[n] += __shfl_xor(v[n], off);
  }
}

// ---- LLC (coherence-point) exchange: sc0 sc1, vectorized, pipelined ----
__device__ __forceinline__ void llc_store_f(float* p, float v){
  asm volatile("global_store_dword %0, %1, off sc0 sc1" :: "v"(p), "v"(v) : "memory");
}
__device__ __forceinline__ f32x2 llc_load2(const float* p){
  f32x2 r;
  asm volatile("global_load_dwordx2 %0, %1, off sc0 sc1" : "=v"(r) : "v"(p) : "memory");
  return r;
}
__device__ __forceinline__ void vm_drain(){
  asm volatile("s_waitcnt vmcnt(0)" ::: "memory");
  __builtin_amdgcn_sched_barrier(0);
}

// Counter barrier: one relaxed agent RMW per block + tid0-only poll of ONE
// line with sleep backoff. Data stores (sc0sc1) are drained (vmcnt0) before
// the arrival RMW issues; readers fetch payloads with sc0sc1 loads.
__device__ __forceinline__ void gbar(unsigned* gcnt, unsigned target){
  asm volatile("s_waitcnt vmcnt(0)" ::: "memory");
  __syncthreads();
  if (threadIdx.x == 0){
    __hip_atomic_fetch_add(gcnt, 1u, __ATOMIC_RELAXED, __HIP_MEMORY_SCOPE_AGENT);
    unsigned v;
    do {
      __builtin_amdgcn_s_sleep(2);
      v = __hip_atomic_load(gcnt, __ATOMIC_RELAXED, __HIP_MEMORY_SCOPE_AGENT);
    } while (v < target);
  }
  __syncthreads();
}

template<int N>
__device__ __forceinline__ void block_reduceN(float* v, float* red){
  #pragma unroll
  for (int off = 32; off > 0; off >>= 1){
    #pragma unroll
    for (int n = 0; n < N; ++n) v[n] += __shfl_xor(v[n], off);
  }
  const int tid = threadIdx.x;
  const int w = tid >> 6;
  __syncthreads();
  if ((tid & 63) == 0){
    #pragma unroll
    for (int n = 0; n < N; ++n) red[n*4 + w] = v[n];
  }
  __syncthreads();
  #pragma unroll
  for (int n = 0; n < N; ++n)
    v[n] = red[n*4+0] + red[n*4+1] + red[n*4+2] + red[n*4+3];
}

// ---------------- precompute GEMM: C[r][c] = dot(A[r,:512], B[c,:512]) -------
#define GBM 64
#define GBN 64
#define GBK 16

__global__ __launch_bounds__(256) void gemm_tn(
    const float* __restrict__ A,   // M x 512 row-major (M = CHUNK*Bn)
    const float* __restrict__ Bm,  // 1536 x 512 row-major
    float* __restrict__ Cm)        // M x 1536
{
  __shared__ __align__(16) float As[GBK][GBM];
  __shared__ __align__(16) float Bs[GBK][GBN];
  const int tid = threadIdx.x;
  const int rm0 = blockIdx.x * GBM;
  const int cn0 = blockIdx.y * GBN;
  const int lr = tid >> 2;
  const int lk = (tid & 3) * 4;
  const int tx = tid & 15;
  const int ty = tid >> 4;
  float acc[4][4] = {};
  const float* Arow = A  + (size_t)(rm0 + lr) * 512 + lk;
  const float* Brow = Bm + (size_t)(cn0 + lr) * 512 + lk;
  for (int k0 = 0; k0 < 512; k0 += GBK){
    const float4 av = *reinterpret_cast<const float4*>(Arow + k0);
    const float4 bv = *reinterpret_cast<const float4*>(Brow + k0);
    __syncthreads();
    As[lk+0][lr]=av.x; As[lk+1][lr]=av.y; As[lk+2][lr]=av.z; As[lk+3][lr]=av.w;
    Bs[lk+0][lr]=bv.x; Bs[lk+1][lr]=bv.y; Bs[lk+2][lr]=bv.z; Bs[lk+3][lr]=bv.w;
    __syncthreads();
    #pragma unroll
    for (int kk = 0; kk < GBK; ++kk){
      const float4 a4 = *reinterpret_cast<const float4*>(&As[kk][tx*4]);
      const float4 b4 = *reinterpret_cast<const float4*>(&Bs[kk][ty*4]);
      const float ar[4] = {a4.x, a4.y, a4.z, a4.w};
      const float br[4] = {b4.x, b4.y, b4.z, b4.w};
      #pragma unroll
      for (int i = 0; i < 4; ++i)
        #pragma unroll
        for (int j = 0; j < 4; ++j)
          acc[i][j] = fmaf(ar[i], br[j], acc[i][j]);
    }
  }
  #pragma unroll
  for (int i = 0; i < 4; ++i){
    float4 st; st.x=acc[i][0]; st.y=acc[i][1]; st.z=acc[i][2]; st.w=acc[i][3];
    *reinterpret_cast<float4*>(&Cm[(size_t)(rm0 + tx*4 + i)*1536 + cn0 + ty*4]) = st;
  }
}

// ------- apply mobius_matvec scaling to P rows (precise libm; runs once) -----
__global__ __launch_bounds__(256) void scale_kernel(
    const float* __restrict__ src,  // nrows x 512 (layer input rows)
    float* __restrict__ P)          // nrows x 1536 (mx, scaled in place)
{
  __shared__ float red[24];
  const int row = blockIdx.x, tid = threadIdx.x;
  const float x0 = src[(size_t)row*512 + tid];
  const float x1 = src[(size_t)row*512 + tid + 256];
  float v[3];
  v[0] = x0*x0 + x1*x1; v[1] = 0.f; v[2] = 0.f;
  block_reduceN<3>(v, red);
  const float xn = sqrtf(v[0] + EPSF);
  const float xc = fminf(fmaxf(xn, -1.0f + 1e-7f), 1.0f - 1e-7f);
  const float artx = 0.5f * (log1pf(xc) - log1pf(-xc));
  float* Prow = P + (size_t)row*1536;
  float p[6];
  #pragma unroll
  for (int g = 0; g < 3; ++g){
    p[2*g]   = Prow[g*512 + tid];
    p[2*g+1] = Prow[g*512 + tid + 256];
  }
  float m[3];
  #pragma unroll
  for (int g = 0; g < 3; ++g) m[g] = p[2*g]*p[2*g] + p[2*g+1]*p[2*g+1];
  block_reduceN<3>(m, red);
  #pragma unroll
  for (int g = 0; g < 3; ++g){
    const float mn = sqrtf(m[g] + EPSF);
    const float s = tanhf(mn / xn * artx) / mn;
    Prow[g*512 + tid]       = s * p[2*g];
    Prow[g*512 + tid + 256] = s * p[2*g+1];
  }
}

// ---------------- persistent recurrence: 16 groups x 16 blocks ---------------
// step: A(mv_rz) | bar | B1(r-chains, z-prefetch) B2(mv_hid || z-chains) | bar
//       | C(finish). lane-major mapping j = 2*l + 128*e.
__global__ __launch_bounds__(256) void recur_kernel(
    const float* __restrict__ Whh,   // (1536,512): [r | hid | z]
    const float* __restrict__ bias,  // (3,512): [b_r, b_h, b_z]
    const float* __restrict__ P,     // CHUNK*Bn x 1536 (scaled x-side)
    const float* __restrict__ hinit, // (B,512) previous h, or nullptr -> zeros
    float* __restrict__ Mrz,         // [2][Bn][1024] double-buffered (LLC)
    float* __restrict__ Mh,          // [Bn][512] (LLC)
    float* __restrict__ outseq,      // (T,B,H)
    float* __restrict__ lastdst,     // (B,H), written at t==Tn-1
    unsigned* __restrict__ cnts,     // NGRP counters, FSTRIDE apart, zeroed
    int t0, int nsteps)
{
  __shared__ __align__(16) float h_lds[NBATCH][HPAD];
  __shared__ __align__(16) float v_lds[NBATCH][HPAD];   // rh
  __shared__ __align__(16) float z_lds[NBATCH][HPAD];   // z gate
  __shared__ float stats[NBATCH][4];  // xn_rh, artx_rh, hn2
  const int bid = blockIdx.x, tid = threadIdx.x;
  const int g = bid >> 4, bl = bid & 15;
  unsigned* gcnt = cnts + (size_t)g * FSTRIDE;
  unsigned ep = 0;
  const int bb = tid >> 6;        // wave id = chain batch (0..3)
  const int l  = tid & 63;        // lane
  const int b4 = g*NBATCH + bb;   // global batch for chain work

  for (int idx = tid; idx < NBATCH*Hn; idx += 256){
    const int b2 = idx >> 9, j = idx & 511;
    h_lds[b2][j] = hinit ? hinit[(size_t)(g*NBATCH + b2)*Hn + j] : 0.f;
  }
  __syncthreads();

  for (int tt = 0; tt < nsteps; ++tt){
    const int t = t0 + tt;
    const int buf = tt & 1;
    f32x2 mz[2][4];   // z-segment prefetch (waves 2-3), B1 -> B2

    // ---------------- A: mv_rz (64 rows x 4 batches per block) ------------
    {
      const int r_i = tid >> 2, bm = tid & 3;
      const int row_local = bl*64 + r_i;                 // 0..1023
      const int wrow = (row_local < 512) ? row_local : row_local + 512;
      const float4* wp = reinterpret_cast<const float4*>(Whh + (size_t)wrow*Hn);
      const float4* hv = reinterpret_cast<const float4*>(&h_lds[bm][0]);
      float a0=0.f,a1=0.f,a2=0.f,a3=0.f;
      #pragma unroll 16
      for (int k = 0; k < 128; ++k){
        const float4 w = wp[k];
        const float4 x = hv[k];
        a0=fmaf(w.x,x.x,a0); a1=fmaf(w.y,x.y,a1);
        a2=fmaf(w.z,x.z,a2); a3=fmaf(w.w,x.w,a3);
      }
      llc_store_f(&Mrz[((size_t)buf*Bn + g*NBATCH + bm)*1024 + row_local],
                  (a0+a1)+(a2+a3));
    }
    gbar(gcnt, (++ep) * GPB);

    // ---------------- B1: r-chain (1 wave/batch) + z prefetch --------------
    {
      const float* Mr = Mrz + ((size_t)buf*Bn + b4)*1024;
      f32x2 mr[4];
      #pragma unroll
      for (int e = 0; e < 4; ++e) mr[e] = llc_load2(Mr + 2*l + 128*e);
      if (bb >= 2){            // prefetch z-segment for B2 (2 batches/wave)
        const int zw = bb - 2;
        #pragma unroll
        for (int i = 0; i < 2; ++i){
          const int bz = g*NBATCH + zw*2 + i;
          const float* Mzp = Mrz + ((size_t)buf*Bn + bz)*1024 + 512;
          #pragma unroll
          for (int e = 0; e < 4; ++e) mz[i][e] = llc_load2(Mzp + 2*l + 128*e);
        }
      }
      const float* prow = P + ((size_t)tt*Bn + b4)*1536;
      f32x2 p2[4], bv2[4], h2[4];
      #pragma unroll
      for (int e = 0; e < 4; ++e){
        p2[e]  = *(const f32x2*)(prow + 2*l + 128*e);
        bv2[e] = *(const f32x2*)(bias + 2*l + 128*e);
        h2[e]  = *(const f32x2*)(&h_lds[bb][2*l + 128*e]);
      }
      vm_drain();
      float m[8], p[8], bv[8], h[8];
      #pragma unroll
      for (int e = 0; e < 4; ++e){
        m[2*e]=mr[e][0];  m[2*e+1]=mr[e][1];
        p[2*e]=p2[e][0];  p[2*e+1]=p2[e][1];
        bv[2*e]=bv2[e][0];bv[2*e+1]=bv2[e][1];
        h[2*e]=h2[e][0];  h[2*e+1]=h2[e][1];
      }
      float v[3];
      v[0]=0.f; v[1]=0.f;
      #pragma unroll
      for (int k = 0; k < 8; ++k){ v[0]=fmaf(h[k],h[k],v[0]); v[1]=fmaf(m[k],m[k],v[1]); }
      red64N<2>(v);
      const float hn2 = v[0];
      const float xn_h = sqrtf(hn2 + EPSF);
      const float artx_h = artanh_fast(xn_h);
      const float m2 = v[1];
      const float mn = sqrtf(m2 + EPSF);
      const float s = tanh_fast(mn/xn_h*artx_h) * (1.f/mn);
      const float x2 = s*s*m2;
      v[0]=0.f; v[1]=0.f;
      #pragma unroll
      for (int k = 0; k < 8; ++k){ v[0]=fmaf(p[k],p[k],v[0]); v[1]=fmaf(s*m[k],p[k],v[1]); }
      red64N<2>(v);
      float na = 1.f + 2.f*v[1] + v[0];
      float nb = 1.f - x2;
      float rden = 1.f / fmaxf(1.f + 2.f*v[1] + x2*v[0], EPSF);
      #pragma unroll
      for (int k = 0; k < 8; ++k) p[k] = (na*s*m[k] + nb*p[k])*rden;   // q
      v[0]=0.f; v[1]=0.f; v[2]=0.f;
      #pragma unroll
      for (int k = 0; k < 8; ++k){
        v[0]=fmaf(p[k],p[k],v[0]); v[1]=fmaf(bv[k],bv[k],v[1]); v[2]=fmaf(p[k],bv[k],v[2]);
      }
      red64N<3>(v);
      na = 1.f + 2.f*v[2] + v[1];
      nb = 1.f - v[0];
      rden = 1.f / fmaxf(1.f + 2.f*v[2] + v[0]*v[1], EPSF);
      v[0] = 0.f;
      #pragma unroll
      for (int k = 0; k < 8; ++k){
        m[k] = (na*p[k] + nb*bv[k])*rden;                              // w
        v[0] = fmaf(m[k], m[k], v[0]);
      }
      red64N<1>(v);
      const float yn = sqrtf(v[0] + EPSF);
      const float sc = artanh_fast(yn) * (1.f/yn);
      v[0] = 0.f;
      #pragma unroll
      for (int k = 0; k < 8; ++k){
        const float r = sigmoid_fast(sc*m[k]);
        m[k] = r*h[k];                                                 // u
        v[0] = fmaf(m[k], m[k], v[0]);
      }
      red64N<1>(v);
      const float u2 = v[0];
      const float wn = sqrtf(u2 + EPSF);
      const float s_rh = tanh_fast(wn/xn_h*artx_h) * (1.f/wn);
      #pragma unroll
      for (int e = 0; e < 4; ++e){
        f32x2 rr; rr[0]=s_rh*m[2*e]; rr[1]=s_rh*m[2*e+1];
        *(f32x2*)(&v_lds[bb][2*l + 128*e]) = rr;
      }
      if (l == 0){
        const float xnrh = sqrtf(s_rh*s_rh*u2 + EPSF);
        stats[bb][0] = xnrh;
        stats[bb][1] = artanh_fast(xnrh);
        stats[bb][2] = hn2;
      }
    }
    __syncthreads();

    // ---------------- B2: mv_hid (waves 0-1)  ||  z-chains (waves 2-3) ----
    if (tid < 128){
      const int rr = tid >> 2, bm = tid & 3;       // 32 rows x 4 batches
      const int wrow = 512 + bl*32 + rr;
      const float4* wp = reinterpret_cast<const float4*>(Whh + (size_t)wrow*Hn);
      const float4* hv = reinterpret_cast<const float4*>(&v_lds[bm][0]);
      float a0=0.f,a1=0.f,a2=0.f,a3=0.f;
      #pragma unroll 16
      for (int k = 0; k < 128; ++k){
        const float4 w = wp[k];
        const float4 x = hv[k];
        a0=fmaf(w.x,x.x,a0); a1=fmaf(w.y,x.y,a1);
        a2=fmaf(w.z,x.z,a2); a3=fmaf(w.w,x.w,a3);
      }
      llc_store_f(&Mh[(size_t)(g*NBATCH + bm)*512 + bl*32 + rr], (a0+a1)+(a2+a3));
    } else {
      const int zw = (tid >> 6) - 2;               // 0 or 1
      #pragma unroll
      for (int i = 0; i < 2; ++i){
        const int bzl = zw*2 + i;
        const int bz = g*NBATCH + bzl;
        const float* prow = P + ((size_t)tt*Bn + bz)*1536;
        float m[8], p[8], bv[8];
        #pragma unroll
        for (int e = 0; e < 4; ++e){
          m[2*e]=mz[i][e][0]; m[2*e+1]=mz[i][e][1];
          const f32x2 pp = *(const f32x2*)(prow + 1024 + 2*l + 128*e);
          p[2*e]=pp[0]; p[2*e+1]=pp[1];
          const f32x2 bb2 = *(const f32x2*)(bias + 1024 + 2*l + 128*e);
          bv[2*e]=bb2[0]; bv[2*e+1]=bb2[1];
        }
        const float hn2 = stats[bzl][2];
        const float xn_h = sqrtf(hn2 + EPSF);
        const float artx_h = artanh_fast(xn_h);
        float v[3];
        v[0] = 0.f;
        #pragma unroll
        for (int k = 0; k < 8; ++k) v[0] = fmaf(m[k],m[k],v[0]);
        red64N<1>(v);
        const float m2 = v[0];
        const float mn = sqrtf(m2 + EPSF);
        const float s = tanh_fast(mn/xn_h*artx_h) * (1.f/mn);
        const float x2 = s*s*m2;
        v[0]=0.f; v[1]=0.f;
        #pragma unroll
        for (int k = 0; k < 8; ++k){ v[0]=fmaf(p[k],p[k],v[0]); v[1]=fmaf(s*m[k],p[k],v[1]); }
        red64N<2>(v);
        float na = 1.f + 2.f*v[1] + v[0];
        float nb = 1.f - x2;
        float rden = 1.f / fmaxf(1.f + 2.f*v[1] + x2*v[0], EPSF);
        #pragma unroll
        for (int k = 0; k < 8; ++k) p[k] = (na*s*m[k] + nb*p[k])*rden;  // q
        v[0]=0.f; v[1]=0.f; v[2]=0.f;
        #pragma unroll
        for (int k = 0; k < 8; ++k){
          v[0]=fmaf(p[k],p[k],v[0]); v[1]=fmaf(bv[k],bv[k],v[1]); v[2]=fmaf(p[k],bv[k],v[2]);
        }
        red64N<3>(v);
        na = 1.f + 2.f*v[2] + v[1];
        nb = 1.f - v[0];
        rden = 1.f / fmaxf(1.f + 2.f*v[2] + v[0]*v[1], EPSF);
        float w2[1] = {0.f};
        #pragma unroll
        for (int k = 0; k < 8; ++k){
          m[k] = (na*p[k] + nb*bv[k])*rden;                             // w
          w2[0] = fmaf(m[k], m[k], w2[0]);
        }
        red64N<1>(w2);
        const float yn = sqrtf(w2[0] + EPSF);
        const float sc = artanh_fast(yn) * (1.f/yn);
        #pragma unroll
        for (int e = 0; e < 4; ++e){
          f32x2 zz;
          zz[0] = sigmoid_fast(sc*m[2*e]);
          zz[1] = sigmoid_fast(sc*m[2*e+1]);
          *(f32x2*)(&z_lds[bzl][2*l + 128*e]) = zz;
        }
      }
    }
    gbar(gcnt, (++ep) * GPB);

    // ---------------- C: finish (1 wave per batch) -------------------------
    {
      f32x2 mh2[4];
      #pragma unroll
      for (int e = 0; e < 4; ++e)
        mh2[e] = llc_load2(Mh + (size_t)b4*512 + 2*l + 128*e);
      const float* prow = P + ((size_t)tt*Bn + b4)*1536;
      f32x2 p2[4], bv2[4], h2[4], z2[4];
      #pragma unroll
      for (int e = 0; e < 4; ++e){
        p2[e]  = *(const f32x2*)(prow + 512 + 2*l + 128*e);
        bv2[e] = *(const f32x2*)(bias + 512 + 2*l + 128*e);
        h2[e]  = *(const f32x2*)(&h_lds[bb][2*l + 128*e]);
        z2[e]  = *(const f32x2*)(&z_lds[bb][2*l + 128*e]);
      }
      vm_drain();
      float m[8], p[8], bv[8], h[8], z[8];
      #pragma unroll
      for (int e = 0; e < 4; ++e){
        m[2*e]=mh2[e][0]; m[2*e+1]=mh2[e][1];
        p[2*e]=p2[e][0];  p[2*e+1]=p2[e][1];
        bv[2*e]=bv2[e][0];bv[2*e+1]=bv2[e][1];
        h[2*e]=h2[e][0];  h[2*e+1]=h2[e][1];
        z[2*e]=z2[e][0];  z[2*e+1]=z2[e][1];
      }
      const float hn2 = stats[bb][2];
      const float xn_rh = stats[bb][0];
      const float artx_rh = stats[bb][1];
      float v[3];
      v[0] = 0.f;
      #pragma unroll
      for (int k = 0; k < 8; ++k) v[0] = fmaf(m[k],m[k],v[0]);
      red64N<1>(v);
      const float m2 = v[0];
      const float mn = sqrtf(m2 + EPSF);
      const float s = tanh_fast(mn/xn_rh*artx_rh) * (1.f/mn);
      const float x2 = s*s*m2;
      v[0]=0.f; v[1]=0.f;
      #pragma unroll
      for (int k = 0; k < 8; ++k){ v[0]=fmaf(p[k],p[k],v[0]); v[1]=fmaf(s*m[k],p[k],v[1]); }
      red64N<2>(v);
      float na = 1.f + 2.f*v[1] + v[0];
      float nb = 1.f - x2;
      float rden = 1.f / fmaxf(1.f + 2.f*v[1] + x2*v[0], EPSF);
      #pragma unroll
      for (int k = 0; k < 8; ++k) p[k] = (na*s*m[k] + nb*p[k])*rden;    // q
      v[0]=0.f; v[1]=0.f; v[2]=0.f;
      #pragma unroll
      for (int k = 0; k < 8; ++k){
        v[0]=fmaf(p[k],p[k],v[0]); v[1]=fmaf(bv[k],bv[k],v[1]); v[2]=fmaf(p[k],bv[k],v[2]);
      }
      red64N<3>(v);
      na = 1.f + 2.f*v[2] + v[1];
      nb = 1.f - v[0];
      rden = 1.f / fmaxf(1.f + 2.f*v[2] + v[0]*v[1], EPSF);
      #pragma unroll
      for (int k = 0; k < 8; ++k) m[k] = (na*p[k] + nb*bv[k])*rden;     // ht
      v[0]=0.f; v[1]=0.f;
      #pragma unroll
      for (int k = 0; k < 8; ++k){ v[0]=fmaf(m[k],m[k],v[0]); v[1]=fmaf(h[k],m[k],v[1]); }
      red64N<2>(v);
      {
        const float y2 = v[0], hht = v[1];
        na = 1.f - 2.f*hht + y2;
        nb = 1.f - hn2;
        rden = 1.f / fmaxf(1.f - 2.f*hht + hn2*y2, EPSF);
        #pragma unroll
        for (int k = 0; k < 8; ++k) p[k] = (na*(-h[k]) + nb*m[k])*rden; // delta
      }
      v[0]=0.f; v[1]=0.f; v[2]=0.f;
      #pragma unroll
      for (int k = 0; k < 8; ++k){
        bv[k] = z[k] * p[k];                                            // wz
        v[0] = fmaf(p[k], p[k], v[0]);
        v[1] = fmaf(bv[k], bv[k], v[1]);
        v[2] = fmaf(h[k], bv[k], v[2]);
      }
      red64N<3>(v);
      const float dn  = sqrtf(v[0] + EPSF);
      const float wzn = sqrtf(v[1] + EPSF);
      const float s_pw = tanh_fast(wzn/dn*artanh_fast(dn)) * (1.f/wzn);
      const float y2f = s_pw*s_pw*v[1];
      const float xyf = s_pw*v[2];
      na = 1.f + 2.f*xyf + y2f;
      nb = 1.f - hn2;
      rden = 1.f / fmaxf(1.f + 2.f*xyf + hn2*y2f, EPSF);
      float* outp = outseq + ((size_t)t*Bn + b4)*512;
      float* lastp = lastdst + (size_t)b4*512;
      #pragma unroll
      for (int e = 0; e < 4; ++e){
        f32x2 hv;
        hv[0] = (na*h[2*e]   + nb*s_pw*bv[2*e])*rden;
        hv[1] = (na*h[2*e+1] + nb*s_pw*bv[2*e+1])*rden;
        *(f32x2*)(&h_lds[bb][2*l + 128*e]) = hv;
        if (bl == 0){
          *(f32x2*)(outp + 2*l + 128*e) = hv;
          if (t == Tn-1) *(f32x2*)(lastp + 2*l + 128*e) = hv;
        }
      }
    }
    __syncthreads();   // protect h_lds before next step's phase A
  }
}

extern "C" void kernel_launch(void* const* d_in, const int* in_sizes, int n_in,
                              void* d_out, int out_size, void* d_ws, size_t ws_size,
                              hipStream_t stream)
{
  const float* inp  = (const float*)d_in[0];   // (T,B,H)
  const float* Wih  = (const float*)d_in[1];   // (L,3H,H)
  const float* Whh  = (const float*)d_in[2];   // (L,3H,H)
  const float* bias = (const float*)d_in[3];   // (L,3,H)
  float* out  = (float*)d_out;                 // (T,B,H)
  float* last = out + (size_t)Tn*Bn*Hn;        // (L,B,H)

  float*    P    = (float*)d_ws;                        // CHUNK*Bn x 1536
  float*    Mrz  = P + (size_t)CHUNK*Bn*1536;           // 2 x Bn x 1024
  float*    Mh   = Mrz + (size_t)2*Bn*1024;             // Bn x 512
  unsigned* cnts = (unsigned*)(Mh + (size_t)Bn*512);    // NGRP * FSTRIDE

  for (int l = 0; l < 2; ++l){
    const float* src   = (l == 0) ? inp : out;
    const float* Wihl  = Wih  + (size_t)l*1536*Hn;
    const float* Whhl  = Whh  + (size_t)l*1536*Hn;
    const float* biasl = bias + (size_t)l*3*Hn;
    for (int c = 0; c < Tn/CHUNK; ++c){
      const int t0 = c*CHUNK;
      const float* srcc = src + (size_t)t0*Bn*Hn;
      dim3 gg(CHUNK*Bn/GBM, 1536/GBN);
      hipLaunchKernelGGL(gemm_tn, gg, dim3(256), 0, stream, srcc, Wihl, P);
      hipLaunchKernelGGL(scale_kernel, dim3(CHUNK*Bn), dim3(256), 0, stream,
                         srcc, P);
      hipMemsetAsync(cnts, 0, (size_t)NGRP*FSTRIDE*sizeof(unsigned), stream);
      const float* hinit = (t0 == 0) ? nullptr
                                     : out + ((size_t)(t0-1))*Bn*Hn;
      hipLaunchKernelGGL(recur_kernel, dim3(NGRP*GPB), dim3(256), 0, stream,
                         Whhl, biasl, P, hinit, Mrz, Mh,
                         out, last + (size_t)l*Bn*Hn, cnts, t0, CHUNK);
    }
  }
}